// Round 4
// baseline (3239.516 us; speedup 1.0000x reference)
//
#include <hip/hip_runtime.h>
#include <cstdint>
#include <cstddef>

// GroupPointNet: FPS -> kNN(20) -> gf=(dp,grouped) -> 3x(conv1x1+lrelu+BN) -> max_k
// B=4, N=8192, M=2048, K=20, C=64. All f32.
// R10: fps = R7 packed compute + R6 keyed-DPP single-barrier reduce (hybrid of the
//      two measured-best designs). Local argmax via post-loop bit-eq scan (all lanes),
//      one keyed (dist,~idx) DPP chain, lane63 -> u64 slot, ONE barrier, register
//      u64 merge tree, pts4[sel] broadcast. Spinners removed (R9: DVFS refuted).

#define B_ 4
#define N_ 8192
#define M_ 2048
#define K_ 20
#define BMK (B_*M_*K_)   // 163840
#define EPS_ 1e-5f

typedef unsigned long long ull;
typedef float f32x2 __attribute__((ext_vector_type(2)));

// ---------- helpers ----------
__device__ __forceinline__ ull packkey(float d, int idx) {
  unsigned int bb = __float_as_uint(d);
  bb ^= (bb & 0x80000000u) ? 0xFFFFFFFFu : 0x80000000u;  // order-preserving map
  return ((ull)bb << 32) | (unsigned int)idx;
}
__device__ __forceinline__ float keymaxf(ull k) {
  unsigned int hb = (unsigned int)(k >> 32);
  unsigned int fb = (hb & 0x80000000u) ? (hb ^ 0x80000000u) : ~hb;
  return __uint_as_float(fb);
}
// keys sorted ascending; caller guarantees key < keys[19]
__device__ __forceinline__ void insert20(ull* keys, ull key) {
#pragma unroll
  for (int i = 19; i > 0; --i) {
    ull lo = keys[i-1];
    keys[i] = (key < lo) ? lo : ((key < keys[i]) ? key : keys[i]);
  }
  keys[0] = (key < keys[0]) ? key : keys[0];
}

// ---------- FPS: 1 block/batch, 512 thr x 16 pts packed, keyed DPP, 1 barrier/iter ----------
// dist >= 0 so float bits compare as u32. Keyed 64-bit (dist_bits, ~idx) max-reduce:
// max over key == argmax with first-index tie-break (~idx: bigger == smaller idx).
#define DPPKEY(CTRL) {                                                               \
    unsigned int nhi = (unsigned int)__builtin_amdgcn_update_dpp(                    \
        (int)hi, (int)hi, CTRL, 0xF, 0xF, false);                                    \
    unsigned int nlo = (unsigned int)__builtin_amdgcn_update_dpp(                    \
        (int)lo, (int)lo, CTRL, 0xF, 0xF, false);                                    \
    bool tk = (nhi > hi) | ((nhi == hi) & (nlo > lo));                               \
    hi = tk ? nhi : hi;                                                              \
    lo = tk ? nlo : lo; }

__global__ __launch_bounds__(512)
void fps_kernel(const float* __restrict__ p, float* __restrict__ p1,
                float* __restrict__ stats) {
#pragma clang fp contract(off)
  const int b = blockIdx.x;
  const int tid = threadIdx.x;
  if (tid < 96) stats[b*96 + tid] = 0.f;       // fused init: 4 blocks x 96 = 384 floats
  const float* pb = p + (size_t)b * (N_*3);
  float* p1b = p1 + (size_t)b * (M_*3);
  __shared__ float4 pts4[N_];                  // 128 KB: broadcast q-fetch
  __shared__ ull slots[2][8];                  // per-wave packed (dist, ~idx), dbuf
  const int wv = tid >> 6;                     // wave 0..7
  const int base = tid * 16;                   // 16 points per thread, as 8 float2 pairs
  f32x2 X[8], Y[8], Z[8], D[8];
#pragma unroll
  for (int j = 0; j < 8; ++j) {
    int i = base + 2*j;
    float x0 = pb[i*3+0], y0 = pb[i*3+1], z0 = pb[i*3+2];
    float x1 = pb[i*3+3], y1 = pb[i*3+4], z1 = pb[i*3+5];
    X[j] = (f32x2){x0, x1};
    Y[j] = (f32x2){y0, y1};
    Z[j] = (f32x2){z0, z1};
    D[j] = (f32x2){1e10f, 1e10f};
    pts4[i]   = make_float4(x0, y0, z0, 0.f);
    pts4[i+1] = make_float4(x1, y1, z1, 0.f);
  }
  float qx = pb[0], qy = pb[1], qz = pb[2];   // idx0 = 0
  if (tid == 0) { p1b[0] = qx; p1b[1] = qy; p1b[2] = qz; }
  __syncthreads();
  for (int t = 1; t < M_; ++t) {
    const int cur = t & 1;
    f32x2 q2x = (f32x2){qx, qx};
    f32x2 q2y = (f32x2){qy, qy};
    f32x2 q2z = (f32x2){qz, qz};
    f32x2 tmx = (f32x2){-1.f, -1.f};
#pragma unroll
    for (int j = 0; j < 8; ++j) {
      // plain vector ops (contract off): per-lane rounding identical to XLA
      // sub -> square -> (dx2+dy2)+dz2 sequence; packs to v_pk_{add,mul}_f32.
      f32x2 dx = X[j] - q2x;
      f32x2 dy = Y[j] - q2y;
      f32x2 dz = Z[j] - q2z;
      f32x2 s = (dx*dx + dy*dy) + dz*dz;
      f32x2 dj = __builtin_elementwise_min(D[j], s);
      D[j] = dj;
      tmx = __builtin_elementwise_max(tmx, dj);
    }
    float tm = fmaxf(tmx.x, tmx.y);
    const unsigned int tmb = __float_as_uint(tm);  // d>=0: bits order == float order
    // local first-index recovery: bit-eq scan over the 16 packed dists (all lanes)
    int fj = 0;
#pragma unroll
    for (int j = 7; j >= 0; --j) {             // descending so lowest index wins
      if (__float_as_uint(D[j].y) == tmb) fj = base + 2*j + 1;
      if (__float_as_uint(D[j].x) == tmb) fj = base + 2*j;
    }
    unsigned int hi = tmb;
    unsigned int lo = ~(unsigned int)fj;
    // keyed wave max-reduce of (dist, ~idx), result in lane 63
    DPPKEY(0x111)  // row_shr:1
    DPPKEY(0x112)  // row_shr:2
    DPPKEY(0x114)  // row_shr:4
    DPPKEY(0x118)  // row_shr:8
    DPPKEY(0x142)  // row_bcast:15
    DPPKEY(0x143)  // row_bcast:31
    if ((tid & 63) == 63) slots[cur][wv] = ((ull)hi << 32) | lo;
    __syncthreads();                           // single barrier: slots ready
    const ull* sp = slots[cur];
    ull a0 = sp[0], a1 = sp[1], a2 = sp[2], a3 = sp[3];
    ull a4 = sp[4], a5 = sp[5], a6 = sp[6], a7 = sp[7];
    ull b0 = (a1 > a0) ? a1 : a0;    // keys never fully equal (distinct idx);
    ull b1 = (a3 > a2) ? a3 : a2;    // equal-dist ties: larger ~idx (smaller idx) wins
    ull b2 = (a5 > a4) ? a5 : a4;
    ull b3 = (a7 > a6) ? a7 : a6;
    ull c0 = (b1 > b0) ? b1 : b0;
    ull c1 = (b3 > b2) ? b3 : b2;
    ull best = (c1 > c0) ? c1 : c0;
    int sel = (int)~(unsigned int)best;        // recover idx
    sel = __builtin_amdgcn_readfirstlane(sel);
    float4 qv = pts4[sel];                     // broadcast ds_read_b128
    qx = qv.x; qy = qv.y; qz = qv.z;
    if (tid == 0) { p1b[t*3+0] = qx; p1b[t*3+1] = qy; p1b[t*3+2] = qz; }
  }
}

// ---------- kNN + gather: 8 queries/block, 32 threads/query, top-20 in regs ----------
#define TILE_ 1024
__global__ __launch_bounds__(256) void knn_kernel(const float* __restrict__ p,
                                                  const float* __restrict__ p1,
                                                  float* __restrict__ gfp) {
  const int blk = blockIdx.x;       // 1024 blocks = 4 batches x 256
  const int b = blk >> 8;
  const int q0 = (blk & 255) * 8;
  __shared__ float4 tile[TILE_];    // 16 KB
  __shared__ ull mk[8*32*20];       // 40 KB
  const int tid = threadIdx.x;
  const int ql = tid >> 5;          // 0..7 query within block
  const int part = tid & 31;        // 0..31 part
  const int m = q0 + ql;
  const float* pb = p + (size_t)b*(N_*3);
  const float* qp_ = p1 + ((size_t)b*M_ + m)*3;
  float qx = qp_[0], qy = qp_[1], qz = qp_[2];
  float qq = __fadd_rn(__fadd_rn(__fmul_rn(qx,qx), __fmul_rn(qy,qy)), __fmul_rn(qz,qz));
  ull keys[20];
#pragma unroll
  for (int i = 0; i < 20; ++i) keys[i] = 0xFF8000007FFFFFFFull;  // pack(+inf, INT_MAX)
  float maxf = __uint_as_float(0x7F800000u);  // +inf
  for (int t0 = 0; t0 < N_; t0 += TILE_) {
    __syncthreads();
    for (int i = tid; i < TILE_; i += 256) {
      float x = pb[(t0+i)*3+0], y = pb[(t0+i)*3+1], z = pb[(t0+i)*3+2];
      float pp = __fadd_rn(__fadd_rn(__fmul_rn(x,x), __fmul_rn(y,y)), __fmul_rn(z,z));
      tile[i] = make_float4(x, y, z, pp);
    }
    __syncthreads();
    const int sbase = part * 32;
    for (int s = 0; s < 32; ++s) {
      int ss = sbase + ((s + part) & 31);       // bank skew across parts
      float4 pt = tile[ss];
      // d = (qq+pp) - 2*qp with qp as fmuladd chain (matches XLA dot emitter)
      float qp = fmaf(pt.z, qz, fmaf(pt.y, qy, __fmul_rn(pt.x, qx)));
      float d = __fsub_rn(__fadd_rn(qq, pt.w), __fmul_rn(2.0f, qp));
      if (d <= maxf) {
        ull key = packkey(d, t0 + ss);
        if (key < keys[19]) { insert20(keys, key); maxf = keymaxf(keys[19]); }
      }
    }
  }
  ull* myslot = &mk[(ql*32 + part)*20];
#pragma unroll
  for (int i = 0; i < 20; ++i) myslot[i] = keys[i];
  __syncthreads();
  if (part == 0) {       // leader merges 32x20 sorted lists
    for (int pp2 = 1; pp2 < 32; ++pp2) {
      const ull* os = &mk[(ql*32 + pp2)*20];
      for (int i = 0; i < 20; ++i) {
        ull k = os[i];
        if (k >= keys[19]) break;    // sorted -> rest can't enter
        insert20(keys, k);
      }
    }
#pragma unroll
    for (int i = 0; i < 20; ++i) myslot[i] = keys[i];
  }
  __syncthreads();
  // write gf planes [6][B*M*K]: c0..2 = grouped - q (dp), c3..5 = grouped
  for (int w = tid; w < 8*K_; w += 256) {
    int ql2 = w / K_;
    int kk = w - ql2*K_;
    ull key = mk[ql2*32*20 + kk];
    int idx = (int)(unsigned int)(key & 0xFFFFFFFFu);
    float gx = pb[idx*3+0], gy = pb[idx*3+1], gz = pb[idx*3+2];
    int m2 = q0 + ql2;
    const float* qv = p1 + ((size_t)b*M_ + m2)*3;
    size_t col = ((size_t)(b*M_ + m2))*K_ + kk;
    gfp[0*BMK + col] = __fsub_rn(gx, qv[0]);
    gfp[1*BMK + col] = __fsub_rn(gy, qv[1]);
    gfp[2*BMK + col] = __fsub_rn(gz, qv[2]);
    gfp[3*BMK + col] = gx;
    gfp[4*BMK + col] = gy;
    gfp[5*BMK + col] = gz;
  }
}

// ---------- stats1: conv1+lrelu per (channel=lane, column), per-channel sums ----------
__global__ __launch_bounds__(256) void stats1_kernel(const float* __restrict__ gfp,
                                                     const float* __restrict__ W1,
                                                     float* __restrict__ stats) {
  const int tid = threadIdx.x;
  const int lane = tid & 63;
  float w[6];
#pragma unroll
  for (int c = 0; c < 6; ++c) w[c] = W1[lane*6 + c];
  const int gw = (blockIdx.x * 256 + tid) >> 6;
  const int nw = (gridDim.x * 256) >> 6;
  float acc = 0.f, accq = 0.f;
  for (int col = gw; col < BMK; col += nw) {
    float y = __fmul_rn(w[0], gfp[0*BMK+col]);
#pragma unroll
    for (int c = 1; c < 6; ++c) y = fmaf(w[c], gfp[c*BMK+col], y);
    float u = (y >= 0.f) ? y : 0.2f*y;
    acc += u;
    accq = fmaf(u, u, accq);
  }
  __shared__ float bs[128];
  if (tid < 128) bs[tid] = 0.f;
  __syncthreads();
  atomicAdd(&bs[lane], acc);
  atomicAdd(&bs[64+lane], accq);
  __syncthreads();
  if (tid < 128) atomicAdd(&stats[tid], bs[tid]);
}

// BN coefficient replication (bit-identical to the old finalize_kernel)
__device__ __forceinline__ void bn_coeff(const float* __restrict__ st,
                                         const float* __restrict__ g,
                                         const float* __restrict__ bb,
                                         int o, float& A, float& C) {
  const float inv = 1.0f / (float)BMK;
  float mean = st[o] * inv;
  float var  = st[64+o] * inv - mean*mean;
  float a = g[o] / sqrtf(var + EPS_);
  A = a;
  C = fmaf(-a, mean, bb[o]);
}

// ---------- pass B (+fused finalize1): gf -> x1 -> conv2 -> lrelu -> u2t[col][64] ----------
__global__ __launch_bounds__(256) void convB_kernel(const float* __restrict__ gfp,
                                                    const float* __restrict__ W1,
                                                    const float* __restrict__ stats,  // layer-1 sums
                                                    const float* __restrict__ g1,
                                                    const float* __restrict__ b1,
                                                    const float* __restrict__ W2,
                                                    float* __restrict__ u2t) {
  __shared__ float sA[64], sC[64];
  const int tid = threadIdx.x;
  if (tid < 64) bn_coeff(stats, g1, b1, tid, sA[tid], sC[tid]);
  __syncthreads();
  const int col = blockIdx.x * 256 + tid;           // 640*256 = 163840 exact
  float gf[6];
#pragma unroll
  for (int c = 0; c < 6; ++c) gf[c] = gfp[c*BMK + col];
  float x1[64];
#pragma unroll
  for (int c = 0; c < 64; ++c) {
    float y = __fmul_rn(W1[c*6+0], gf[0]);
#pragma unroll
    for (int i = 1; i < 6; ++i) y = fmaf(W1[c*6+i], gf[i], y);
    float u = (y >= 0.f) ? y : 0.2f*y;
    x1[c] = fmaf(sA[c], u, sC[c]);
  }
  float* ob = u2t + (size_t)col * 64;
  for (int o4 = 0; o4 < 16; ++o4) {
    float y0 = 0.f, y1 = 0.f, y2 = 0.f, y3 = 0.f;
#pragma unroll
    for (int c = 0; c < 64; ++c) {
      float xc = x1[c];
      y0 = fmaf(W2[(o4*4+0)*64+c], xc, y0);
      y1 = fmaf(W2[(o4*4+1)*64+c], xc, y1);
      y2 = fmaf(W2[(o4*4+2)*64+c], xc, y2);
      y3 = fmaf(W2[(o4*4+3)*64+c], xc, y3);
    }
    float4 v;
    v.x = (y0 >= 0.f) ? y0 : 0.2f*y0;
    v.y = (y1 >= 0.f) ? y1 : 0.2f*y1;
    v.z = (y2 >= 0.f) ? y2 : 0.2f*y2;
    v.w = (y3 >= 0.f) ? y3 : 0.2f*y3;
    ((float4*)ob)[o4] = v;
  }
}

// ---------- stats2: per-channel sums of u2 (coalesced float4) ----------
__global__ __launch_bounds__(256) void stats2_kernel(const float* __restrict__ u2t,
                                                     float* __restrict__ stats) {
  const int g = blockIdx.x * 256 + threadIdx.x;
  const int ntot = gridDim.x * 256;               // 131072 (x4 floats ≡ 0 mod 64)
  const float4* u4 = (const float4*)u2t;
  const int nf4 = BMK * 16;
  float a0=0,a1=0,a2=0,a3=0,s0=0,s1=0,s2=0,s3=0;
  for (int i = g; i < nf4; i += ntot) {
    float4 v = u4[i];
    a0 += v.x; s0 = fmaf(v.x, v.x, s0);
    a1 += v.y; s1 = fmaf(v.y, v.y, s1);
    a2 += v.z; s2 = fmaf(v.z, v.z, s2);
    a3 += v.w; s3 = fmaf(v.w, v.w, s3);
  }
  const int c0 = (4*g) & 63;
  __shared__ float bs[128];
  if (threadIdx.x < 128) bs[threadIdx.x] = 0.f;
  __syncthreads();
  atomicAdd(&bs[c0+0], a0); atomicAdd(&bs[c0+1], a1);
  atomicAdd(&bs[c0+2], a2); atomicAdd(&bs[c0+3], a3);
  atomicAdd(&bs[64+c0+0], s0); atomicAdd(&bs[64+c0+1], s1);
  atomicAdd(&bs[64+c0+2], s2); atomicAdd(&bs[64+c0+3], s3);
  __syncthreads();
  if (threadIdx.x < 128) atomicAdd(&stats[threadIdx.x], bs[threadIdx.x]);
}

// ---------- stats3 (+fused finalize2/fold3): u3 = lrelu(W3f·u2 + b3f), sums ----------
__global__ __launch_bounds__(256) void stats3_kernel(const float* __restrict__ u2t,
                                                     const float* __restrict__ W3,
                                                     const float* __restrict__ stats2v, // layer-2 sums
                                                     const float* __restrict__ g2,
                                                     const float* __restrict__ b2,
                                                     float* __restrict__ stats) {
  __shared__ float sA2[64], sC2[64];
  const int tid = threadIdx.x;
  if (tid < 64) bn_coeff(stats2v, g2, b2, tid, sA2[tid], sC2[tid]);
  __syncthreads();
  const int lane = tid & 63;
  float w[64];
#pragma unroll
  for (int c = 0; c < 64; ++c) w[c] = W3[lane*64 + c] * sA2[c];   // == W3f
  float bb = 0.f;
#pragma unroll
  for (int c = 0; c < 64; ++c) bb = fmaf(W3[lane*64 + c], sC2[c], bb);  // == b3f
  const int gw = (blockIdx.x*256 + tid) >> 6;
  const int nw = (gridDim.x*256) >> 6;
  float acc = 0.f, accq = 0.f;
  for (int col = gw; col < BMK; col += nw) {
    const float4* u4 = (const float4*)(u2t + (size_t)col*64);
    float y = bb;
#pragma unroll
    for (int c4 = 0; c4 < 16; ++c4) {
      float4 v = u4[c4];
      y = fmaf(w[4*c4+0], v.x, y);
      y = fmaf(w[4*c4+1], v.y, y);
      y = fmaf(w[4*c4+2], v.z, y);
      y = fmaf(w[4*c4+3], v.w, y);
    }
    float u = (y >= 0.f) ? y : 0.2f*y;
    acc += u; accq = fmaf(u, u, accq);
  }
  __shared__ float bs[128];
  if (tid < 128) bs[tid] = 0.f;
  __syncthreads();
  atomicAdd(&bs[lane], acc);
  atomicAdd(&bs[64+lane], accq);
  __syncthreads();
  if (tid < 128) atomicAdd(&stats[tid], bs[tid]);
}

// ---------- out (+fused finalize3): per (b,m) wave, recompute u3 over k, max, BN3 ----------
__global__ __launch_bounds__(256) void out_kernel(const float* __restrict__ u2t,
                                                  const float* __restrict__ W3,
                                                  const float* __restrict__ stats2v,
                                                  const float* __restrict__ g2,
                                                  const float* __restrict__ b2,
                                                  const float* __restrict__ stats3v,
                                                  const float* __restrict__ g3,
                                                  const float* __restrict__ b3,
                                                  float* __restrict__ out) {
  __shared__ float sA2[64], sC2[64];
  const int tid = threadIdx.x;
  if (tid < 64) bn_coeff(stats2v, g2, b2, tid, sA2[tid], sC2[tid]);
  __syncthreads();
  const int lane = tid & 63;
  const int wv = (blockIdx.x*256 + tid) >> 6;   // 0..8191 = b*M + m
  float w[64];
#pragma unroll
  for (int c = 0; c < 64; ++c) w[c] = W3[lane*64 + c] * sA2[c];   // == W3f
  float bb = 0.f;
#pragma unroll
  for (int c = 0; c < 64; ++c) bb = fmaf(W3[lane*64 + c], sC2[c], bb);  // == b3f
  float mx = -3.4e38f, mn = 3.4e38f;
  for (int k = 0; k < K_; ++k) {
    const float4* u4 = (const float4*)(u2t + ((size_t)wv*K_ + k)*64);
    float y = bb;
#pragma unroll
    for (int c4 = 0; c4 < 16; ++c4) {
      float4 v = u4[c4];
      y = fmaf(w[4*c4+0], v.x, y);
      y = fmaf(w[4*c4+1], v.y, y);
      y = fmaf(w[4*c4+2], v.z, y);
      y = fmaf(w[4*c4+3], v.w, y);
    }
    float u = (y >= 0.f) ? y : 0.2f*y;
    mx = fmaxf(mx, u); mn = fminf(mn, u);
  }
  float A3, C3;
  bn_coeff(stats3v, g3, b3, lane, A3, C3);
  float r = (A3 >= 0.f) ? mx : mn;   // affine commutes with max when a>=0
  int b = wv >> 11, m = wv & 2047;
  out[((size_t)(b*64 + lane))*M_ + m] = fmaf(A3, r, C3);
}

// ---------- launch ----------
extern "C" void kernel_launch(void* const* d_in, const int* in_sizes, int n_in,
                              void* d_out, int out_size, void* d_ws, size_t ws_size,
                              hipStream_t stream) {
  const float* p  = (const float*)d_in[0];
  const float* W1 = (const float*)d_in[1];
  const float* g1 = (const float*)d_in[2];
  const float* b1 = (const float*)d_in[3];
  const float* W2 = (const float*)d_in[4];
  const float* g2 = (const float*)d_in[5];
  const float* b2 = (const float*)d_in[6];
  const float* W3 = (const float*)d_in[7];
  const float* g3 = (const float*)d_in[8];
  const float* b3 = (const float*)d_in[9];
  float* out = (float*)d_out;
  char* ws = (char*)d_ws;

  // workspace layout (~46.2 MB total)
  float* p1    = (float*)(ws);                 // 98,304 B
  float* gfp   = (float*)(ws + 131072);        // 3,932,160 B
  float* u2t   = (float*)(ws + 4194304);       // 41,943,040 B
  float* stats = (float*)(ws + 46137344);      // 384 f (sum/sq x3 layers)

  hipLaunchKernelGGL(fps_kernel,    dim3(4),    dim3(512), 0, stream, p, p1, stats);
  hipLaunchKernelGGL(knn_kernel,    dim3(1024), dim3(256), 0, stream, p, p1, gfp);
  hipLaunchKernelGGL(stats1_kernel, dim3(256),  dim3(256), 0, stream, gfp, W1, stats);
  hipLaunchKernelGGL(convB_kernel,  dim3(640),  dim3(256), 0, stream, gfp, W1, stats, g1, b1, W2, u2t);
  hipLaunchKernelGGL(stats2_kernel, dim3(512),  dim3(256), 0, stream, u2t, stats+128);
  hipLaunchKernelGGL(stats3_kernel, dim3(512),  dim3(256), 0, stream, u2t, W3, stats+128, g2, b2, stats+256);
  hipLaunchKernelGGL(out_kernel,    dim3(2048), dim3(256), 0, stream, u2t, W3, stats+128, g2, b2, stats+256, g3, b3, out);
}

// Round 5
// 2456.834 us; speedup vs baseline: 1.3186x; 1.3186x over previous
//
#include <hip/hip_runtime.h>
#include <cstdint>
#include <cstddef>

// GroupPointNet: FPS -> kNN(20) -> gf=(dp,grouped) -> 3x(conv1x1+lrelu+BN) -> max_k
// B=4, N=8192, M=2048, K=20, C=64. All f32.
// R11: fps reverted to R7 (measured best, 1802us). NEW: fps+knn+stats1 fused into one
//      kernel. 4 fps blocks publish progress (agent release every 64 iters); 248
//      persistent knn blocks (1 block/CU via 131KB LDS union -> all 252 resident,
//      no dispatch-order deadlock) spin+acquire, run knn chunks ordered by readiness,
//      and fold stats1 sums in-block. 7 launches -> 5 + memset; knn+stats1 fully
//      hidden under fps's 1.8ms shadow.

#define B_ 4
#define N_ 8192
#define M_ 2048
#define K_ 20
#define BMK (B_*M_*K_)   // 163840
#define EPS_ 1e-5f
#define TILE_ 1024
#define PERS 248

typedef unsigned long long ull;
typedef float f32x2 __attribute__((ext_vector_type(2)));

// ---------- helpers ----------
__device__ __forceinline__ ull packkey(float d, int idx) {
  unsigned int bb = __float_as_uint(d);
  bb ^= (bb & 0x80000000u) ? 0xFFFFFFFFu : 0x80000000u;  // order-preserving map
  return ((ull)bb << 32) | (unsigned int)idx;
}
__device__ __forceinline__ float keymaxf(ull k) {
  unsigned int hb = (unsigned int)(k >> 32);
  unsigned int fb = (hb & 0x80000000u) ? (hb ^ 0x80000000u) : ~hb;
  return __uint_as_float(fb);
}
// keys sorted ascending; caller guarantees key < keys[19]
__device__ __forceinline__ void insert20(ull* keys, ull key) {
#pragma unroll
  for (int i = 19; i > 0; --i) {
    ull lo = keys[i-1];
    keys[i] = (key < lo) ? lo : ((key < keys[i]) ? key : keys[i]);
  }
  keys[0] = (key < keys[0]) ? key : keys[0];
}

#define DPPMAXU(V, CTRL) {                                                           \
    unsigned int nh = (unsigned int)__builtin_amdgcn_update_dpp(                     \
        (int)V, (int)V, CTRL, 0xF, 0xF, false);                                      \
    V = (nh > V) ? nh : V; }

// ---------- fused fps + knn + stats1 ----------
// blocks 0..3: R7 fps (512thr x 16pts packed, value DPP + atomicMin, 2 barriers/iter)
// blocks 4..251: persistent knn consumers, chunks ordered by readiness.
__global__ __launch_bounds__(512)
void fpsknn_kernel(const float* __restrict__ p, float* __restrict__ p1,
                   float* __restrict__ gfp, const float* __restrict__ W1,
                   float* __restrict__ stats, int* __restrict__ prog) {
  __shared__ union {
    struct { float4 pts4[N_]; unsigned int slotsv[2][8]; int idxsel[2]; } f;  // 131144 B
    struct { float4 tile[TILE_]; ull mk[8*32*20]; float bs[128]; } k;         // 57856 B
  } sm;
  const int tid = threadIdx.x;

  if (blockIdx.x < B_) {
    // ================= FPS role (R7 verbatim; stats-init moved to memset) ==========
#pragma clang fp contract(off)
    const int b = blockIdx.x;
    const float* pb = p + (size_t)b * (N_*3);
    float* p1b = p1 + (size_t)b * (M_*3);
    float4* pts4 = sm.f.pts4;
    const int wv = tid >> 6;                   // wave 0..7
    const int base = tid * 16;                 // 16 points per thread, 8 float2 pairs
    f32x2 X[8], Y[8], Z[8], D[8];
#pragma unroll
    for (int j = 0; j < 8; ++j) {
      int i = base + 2*j;
      float x0 = pb[i*3+0], y0 = pb[i*3+1], z0 = pb[i*3+2];
      float x1 = pb[i*3+3], y1 = pb[i*3+4], z1 = pb[i*3+5];
      X[j] = (f32x2){x0, x1};
      Y[j] = (f32x2){y0, y1};
      Z[j] = (f32x2){z0, z1};
      D[j] = (f32x2){1e10f, 1e10f};
      pts4[i]   = make_float4(x0, y0, z0, 0.f);
      pts4[i+1] = make_float4(x1, y1, z1, 0.f);
    }
    if (tid < 2) sm.f.idxsel[tid] = 0x7FFFFFFF;
    float qx = pb[0], qy = pb[1], qz = pb[2];  // idx0 = 0
    if (tid == 0) { p1b[0] = qx; p1b[1] = qy; p1b[2] = qz; }
    __syncthreads();
    for (int t = 1; t < M_; ++t) {
      const int cur = t & 1;
      f32x2 q2x = (f32x2){qx, qx};
      f32x2 q2y = (f32x2){qy, qy};
      f32x2 q2z = (f32x2){qz, qz};
      f32x2 tmx = (f32x2){-1.f, -1.f};
#pragma unroll
      for (int j = 0; j < 8; ++j) {
        // plain vector ops (contract off): per-lane rounding identical to XLA
        f32x2 dx = X[j] - q2x;
        f32x2 dy = Y[j] - q2y;
        f32x2 dz = Z[j] - q2z;
        f32x2 s = (dx*dx + dy*dy) + dz*dz;
        f32x2 dj = __builtin_elementwise_min(D[j], s);
        D[j] = dj;
        tmx = __builtin_elementwise_max(tmx, dj);
      }
      float tm = fmaxf(tmx.x, tmx.y);
      const unsigned int tmb = __float_as_uint(tm);  // d>=0: bit order == float order
      unsigned int hv = tmb;
      DPPMAXU(hv, 0x111)  // row_shr:1
      DPPMAXU(hv, 0x112)  // row_shr:2
      DPPMAXU(hv, 0x114)  // row_shr:4
      DPPMAXU(hv, 0x118)  // row_shr:8
      DPPMAXU(hv, 0x142)  // row_bcast:15
      DPPMAXU(hv, 0x143)  // row_bcast:31
      if ((tid & 63) == 63) sm.f.slotsv[cur][wv] = hv;
      __syncthreads();                         // barrier 1: slots ready
      if (tid == 0) sm.f.idxsel[cur ^ 1] = 0x7FFFFFFF;   // prep slot for t+1
      unsigned int g = sm.f.slotsv[cur][0];
#pragma unroll
      for (int j = 1; j < 8; ++j) { unsigned int s2 = sm.f.slotsv[cur][j]; g = (s2 > g) ? s2 : g; }
      if (tmb == g) {                          // holder(s) of the max
        int fj = 0x7FFFFFFF;
#pragma unroll
        for (int j = 7; j >= 0; --j) {         // descending so lowest index wins
          if (__float_as_uint(D[j].y) == g) fj = base + 2*j + 1;
          if (__float_as_uint(D[j].x) == g) fj = base + 2*j;
        }
        atomicMin(&sm.f.idxsel[cur], fj);      // global first-index tie-break
      }
      __syncthreads();                         // barrier 2: index final
      int sel = sm.f.idxsel[cur];
      sel = __builtin_amdgcn_readfirstlane(sel);
      float4 qv = pts4[sel];                   // broadcast ds_read_b128
      qx = qv.x; qy = qv.y; qz = qv.z;
      if (tid == 0) {
        p1b[t*3+0] = qx; p1b[t*3+1] = qy; p1b[t*3+2] = qz;
        if ((t & 63) == 63)
          __hip_atomic_store(&prog[b], t, __ATOMIC_RELEASE, __HIP_MEMORY_SCOPE_AGENT);
      }
    }
    if (tid == 0)
      __hip_atomic_store(&prog[b], M_, __ATOMIC_RELEASE, __HIP_MEMORY_SCOPE_AGENT);
    return;
  }

  // ================= kNN + stats1 role (persistent consumer) ======================
  float4* tile = sm.k.tile;
  ull* mk = sm.k.mk;
  float* gfl = (float*)sm.k.tile;              // overlays tile after the scan phase
  float* bs = sm.k.bs;
  for (int ord = (int)blockIdx.x - B_; ord < 1024; ord += PERS) {
    const int b = ord & 3;                     // readiness-ordered chunks per block
    const int q0 = (ord >> 2) * 8;
    if (tid == 0) {
      while (__hip_atomic_load(&prog[b], __ATOMIC_ACQUIRE, __HIP_MEMORY_SCOPE_AGENT) < q0 + 7)
        __builtin_amdgcn_s_sleep(16);
    }
    __syncthreads();
    { int pv = __hip_atomic_load(&prog[b], __ATOMIC_ACQUIRE, __HIP_MEMORY_SCOPE_AGENT);
      asm volatile("" :: "v"(pv)); }           // per-thread acquire, kept live

    const int ql = (tid >> 5) & 7;             // query within block (tid<256 active)
    const int part = tid & 31;
    const int m = q0 + ql;
    const float* pb = p + (size_t)b*(N_*3);
    const float* qp_ = p1 + ((size_t)b*M_ + m)*3;
    float qx = qp_[0], qy = qp_[1], qz = qp_[2];
    float qq = __fadd_rn(__fadd_rn(__fmul_rn(qx,qx), __fmul_rn(qy,qy)), __fmul_rn(qz,qz));
    ull keys[20];
#pragma unroll
    for (int i = 0; i < 20; ++i) keys[i] = 0xFF8000007FFFFFFFull;  // pack(+inf, INT_MAX)
    float maxf = __uint_as_float(0x7F800000u);  // +inf
    for (int t0 = 0; t0 < N_; t0 += TILE_) {
      __syncthreads();                          // also guards gfl/tile reuse across chunks
      for (int i = tid; i < TILE_; i += 512) {
        float x = pb[(t0+i)*3+0], y = pb[(t0+i)*3+1], z = pb[(t0+i)*3+2];
        float pp = __fadd_rn(__fadd_rn(__fmul_rn(x,x), __fmul_rn(y,y)), __fmul_rn(z,z));
        tile[i] = make_float4(x, y, z, pp);
      }
      __syncthreads();
      if (tid < 256) {
        const int sbase = part * 32;
        for (int s = 0; s < 32; ++s) {
          int ss = sbase + ((s + part) & 31);   // bank skew across parts
          float4 pt = tile[ss];
          float qp = fmaf(pt.z, qz, fmaf(pt.y, qy, __fmul_rn(pt.x, qx)));
          float d = __fsub_rn(__fadd_rn(qq, pt.w), __fmul_rn(2.0f, qp));
          if (d <= maxf) {
            ull key = packkey(d, t0 + ss);
            if (key < keys[19]) { insert20(keys, key); maxf = keymaxf(keys[19]); }
          }
        }
      }
    }
    if (tid < 256) {
      ull* myslot = &mk[(ql*32 + part)*20];
#pragma unroll
      for (int i = 0; i < 20; ++i) myslot[i] = keys[i];
    }
    __syncthreads();
    if (tid < 256 && part == 0) {   // leader merges 32x20 sorted lists
      for (int pp2 = 1; pp2 < 32; ++pp2) {
        const ull* os = &mk[(ql*32 + pp2)*20];
        for (int i = 0; i < 20; ++i) {
          ull k = os[i];
          if (k >= keys[19]) break;    // sorted -> rest can't enter
          insert20(keys, k);
        }
      }
      ull* myslot = &mk[(ql*32)*20];
#pragma unroll
      for (int i = 0; i < 20; ++i) myslot[i] = keys[i];
    }
    __syncthreads();
    // gf write (global planes) + LDS stash for the stats1 tail
    for (int w = tid; w < 8*K_; w += 512) {
      int ql2 = w / K_;
      int kk = w - ql2*K_;
      ull key = mk[ql2*32*20 + kk];
      int idx = (int)(unsigned int)(key & 0xFFFFFFFFu);
      float gx = pb[idx*3+0], gy = pb[idx*3+1], gz = pb[idx*3+2];
      int m2 = q0 + ql2;
      const float* qv = p1 + ((size_t)b*M_ + m2)*3;
      size_t col = ((size_t)(b*M_ + m2))*K_ + kk;
      float d0 = __fsub_rn(gx, qv[0]);
      float d1 = __fsub_rn(gy, qv[1]);
      float d2 = __fsub_rn(gz, qv[2]);
      gfp[0*BMK + col] = d0;
      gfp[1*BMK + col] = d1;
      gfp[2*BMK + col] = d2;
      gfp[3*BMK + col] = gx;
      gfp[4*BMK + col] = gy;
      gfp[5*BMK + col] = gz;
      gfl[w*6+0] = d0; gfl[w*6+1] = d1; gfl[w*6+2] = d2;
      gfl[w*6+3] = gx; gfl[w*6+4] = gy; gfl[w*6+5] = gz;
    }
    __syncthreads();
    // stats1 tail: 8 grps x 64 lanes(=channels), 20 cols each (same fmaf sequence)
    {
      const int lane = tid & 63;
      const int grp = tid >> 6;
      float w1r[6];
#pragma unroll
      for (int c = 0; c < 6; ++c) w1r[c] = W1[lane*6 + c];
      float acc = 0.f, accq = 0.f;
      for (int cc = 0; cc < 20; ++cc) {
        const float* gv = &gfl[(grp*20 + cc)*6];
        float y = __fmul_rn(w1r[0], gv[0]);
#pragma unroll
        for (int c = 1; c < 6; ++c) y = fmaf(w1r[c], gv[c], y);
        float u = (y >= 0.f) ? y : 0.2f*y;
        acc += u;
        accq = fmaf(u, u, accq);
      }
      if (tid < 128) bs[tid] = 0.f;
      __syncthreads();
      atomicAdd(&bs[lane], acc);
      atomicAdd(&bs[64+lane], accq);
      __syncthreads();
      if (tid < 128) atomicAdd(&stats[tid], bs[tid]);
    }
  }
}

// BN coefficient replication (bit-identical to the old finalize_kernel)
__device__ __forceinline__ void bn_coeff(const float* __restrict__ st,
                                         const float* __restrict__ g,
                                         const float* __restrict__ bb,
                                         int o, float& A, float& C) {
  const float inv = 1.0f / (float)BMK;
  float mean = st[o] * inv;
  float var  = st[64+o] * inv - mean*mean;
  float a = g[o] / sqrtf(var + EPS_);
  A = a;
  C = fmaf(-a, mean, bb[o]);
}

// ---------- pass B (+fused finalize1): gf -> x1 -> conv2 -> lrelu -> u2t[col][64] ----------
__global__ __launch_bounds__(256) void convB_kernel(const float* __restrict__ gfp,
                                                    const float* __restrict__ W1,
                                                    const float* __restrict__ stats,  // layer-1 sums
                                                    const float* __restrict__ g1,
                                                    const float* __restrict__ b1,
                                                    const float* __restrict__ W2,
                                                    float* __restrict__ u2t) {
  __shared__ float sA[64], sC[64];
  const int tid = threadIdx.x;
  if (tid < 64) bn_coeff(stats, g1, b1, tid, sA[tid], sC[tid]);
  __syncthreads();
  const int col = blockIdx.x * 256 + tid;           // 640*256 = 163840 exact
  float gf[6];
#pragma unroll
  for (int c = 0; c < 6; ++c) gf[c] = gfp[c*BMK + col];
  float x1[64];
#pragma unroll
  for (int c = 0; c < 64; ++c) {
    float y = __fmul_rn(W1[c*6+0], gf[0]);
#pragma unroll
    for (int i = 1; i < 6; ++i) y = fmaf(W1[c*6+i], gf[i], y);
    float u = (y >= 0.f) ? y : 0.2f*y;
    x1[c] = fmaf(sA[c], u, sC[c]);
  }
  float* ob = u2t + (size_t)col * 64;
  for (int o4 = 0; o4 < 16; ++o4) {
    float y0 = 0.f, y1 = 0.f, y2 = 0.f, y3 = 0.f;
#pragma unroll
    for (int c = 0; c < 64; ++c) {
      float xc = x1[c];
      y0 = fmaf(W2[(o4*4+0)*64+c], xc, y0);
      y1 = fmaf(W2[(o4*4+1)*64+c], xc, y1);
      y2 = fmaf(W2[(o4*4+2)*64+c], xc, y2);
      y3 = fmaf(W2[(o4*4+3)*64+c], xc, y3);
    }
    float4 v;
    v.x = (y0 >= 0.f) ? y0 : 0.2f*y0;
    v.y = (y1 >= 0.f) ? y1 : 0.2f*y1;
    v.z = (y2 >= 0.f) ? y2 : 0.2f*y2;
    v.w = (y3 >= 0.f) ? y3 : 0.2f*y3;
    ((float4*)ob)[o4] = v;
  }
}

// ---------- stats2: per-channel sums of u2 (coalesced float4) ----------
__global__ __launch_bounds__(256) void stats2_kernel(const float* __restrict__ u2t,
                                                     float* __restrict__ stats) {
  const int g = blockIdx.x * 256 + threadIdx.x;
  const int ntot = gridDim.x * 256;               // 131072 (x4 floats ≡ 0 mod 64)
  const float4* u4 = (const float4*)u2t;
  const int nf4 = BMK * 16;
  float a0=0,a1=0,a2=0,a3=0,s0=0,s1=0,s2=0,s3=0;
  for (int i = g; i < nf4; i += ntot) {
    float4 v = u4[i];
    a0 += v.x; s0 = fmaf(v.x, v.x, s0);
    a1 += v.y; s1 = fmaf(v.y, v.y, s1);
    a2 += v.z; s2 = fmaf(v.z, v.z, s2);
    a3 += v.w; s3 = fmaf(v.w, v.w, s3);
  }
  const int c0 = (4*g) & 63;
  __shared__ float bs[128];
  if (threadIdx.x < 128) bs[threadIdx.x] = 0.f;
  __syncthreads();
  atomicAdd(&bs[c0+0], a0); atomicAdd(&bs[c0+1], a1);
  atomicAdd(&bs[c0+2], a2); atomicAdd(&bs[c0+3], a3);
  atomicAdd(&bs[64+c0+0], s0); atomicAdd(&bs[64+c0+1], s1);
  atomicAdd(&bs[64+c0+2], s2); atomicAdd(&bs[64+c0+3], s3);
  __syncthreads();
  if (threadIdx.x < 128) atomicAdd(&stats[threadIdx.x], bs[threadIdx.x]);
}

// ---------- stats3 (+fused finalize2/fold3): u3 = lrelu(W3f·u2 + b3f), sums ----------
__global__ __launch_bounds__(256) void stats3_kernel(const float* __restrict__ u2t,
                                                     const float* __restrict__ W3,
                                                     const float* __restrict__ stats2v, // layer-2 sums
                                                     const float* __restrict__ g2,
                                                     const float* __restrict__ b2,
                                                     float* __restrict__ stats) {
  __shared__ float sA2[64], sC2[64];
  const int tid = threadIdx.x;
  if (tid < 64) bn_coeff(stats2v, g2, b2, tid, sA2[tid], sC2[tid]);
  __syncthreads();
  const int lane = tid & 63;
  float w[64];
#pragma unroll
  for (int c = 0; c < 64; ++c) w[c] = W3[lane*64 + c] * sA2[c];   // == W3f
  float bb = 0.f;
#pragma unroll
  for (int c = 0; c < 64; ++c) bb = fmaf(W3[lane*64 + c], sC2[c], bb);  // == b3f
  const int gw = (blockIdx.x*256 + tid) >> 6;
  const int nw = (gridDim.x*256) >> 6;
  float acc = 0.f, accq = 0.f;
  for (int col = gw; col < BMK; col += nw) {
    const float4* u4 = (const float4*)(u2t + (size_t)col*64);
    float y = bb;
#pragma unroll
    for (int c4 = 0; c4 < 16; ++c4) {
      float4 v = u4[c4];
      y = fmaf(w[4*c4+0], v.x, y);
      y = fmaf(w[4*c4+1], v.y, y);
      y = fmaf(w[4*c4+2], v.z, y);
      y = fmaf(w[4*c4+3], v.w, y);
    }
    float u = (y >= 0.f) ? y : 0.2f*y;
    acc += u; accq = fmaf(u, u, accq);
  }
  __shared__ float bs[128];
  if (tid < 128) bs[tid] = 0.f;
  __syncthreads();
  atomicAdd(&bs[lane], acc);
  atomicAdd(&bs[64+lane], accq);
  __syncthreads();
  if (tid < 128) atomicAdd(&stats[tid], bs[tid]);
}

// ---------- out (+fused finalize3): per (b,m) wave, recompute u3 over k, max, BN3 ----------
__global__ __launch_bounds__(256) void out_kernel(const float* __restrict__ u2t,
                                                  const float* __restrict__ W3,
                                                  const float* __restrict__ stats2v,
                                                  const float* __restrict__ g2,
                                                  const float* __restrict__ b2,
                                                  const float* __restrict__ stats3v,
                                                  const float* __restrict__ g3,
                                                  const float* __restrict__ b3,
                                                  float* __restrict__ out) {
  __shared__ float sA2[64], sC2[64];
  const int tid = threadIdx.x;
  if (tid < 64) bn_coeff(stats2v, g2, b2, tid, sA2[tid], sC2[tid]);
  __syncthreads();
  const int lane = tid & 63;
  const int wv = (blockIdx.x*256 + tid) >> 6;   // 0..8191 = b*M + m
  float w[64];
#pragma unroll
  for (int c = 0; c < 64; ++c) w[c] = W3[lane*64 + c] * sA2[c];   // == W3f
  float bb = 0.f;
#pragma unroll
  for (int c = 0; c < 64; ++c) bb = fmaf(W3[lane*64 + c], sC2[c], bb);  // == b3f
  float mx = -3.4e38f, mn = 3.4e38f;
  for (int k = 0; k < K_; ++k) {
    const float4* u4 = (const float4*)(u2t + ((size_t)wv*K_ + k)*64);
    float y = bb;
#pragma unroll
    for (int c4 = 0; c4 < 16; ++c4) {
      float4 v = u4[c4];
      y = fmaf(w[4*c4+0], v.x, y);
      y = fmaf(w[4*c4+1], v.y, y);
      y = fmaf(w[4*c4+2], v.z, y);
      y = fmaf(w[4*c4+3], v.w, y);
    }
    float u = (y >= 0.f) ? y : 0.2f*y;
    mx = fmaxf(mx, u); mn = fminf(mn, u);
  }
  float A3, C3;
  bn_coeff(stats3v, g3, b3, lane, A3, C3);
  float r = (A3 >= 0.f) ? mx : mn;   // affine commutes with max when a>=0
  int b = wv >> 11, m = wv & 2047;
  out[((size_t)(b*64 + lane))*M_ + m] = fmaf(A3, r, C3);
}

// ---------- launch ----------
extern "C" void kernel_launch(void* const* d_in, const int* in_sizes, int n_in,
                              void* d_out, int out_size, void* d_ws, size_t ws_size,
                              hipStream_t stream) {
  const float* p  = (const float*)d_in[0];
  const float* W1 = (const float*)d_in[1];
  const float* g1 = (const float*)d_in[2];
  const float* b1 = (const float*)d_in[3];
  const float* W2 = (const float*)d_in[4];
  const float* g2 = (const float*)d_in[5];
  const float* b2 = (const float*)d_in[6];
  const float* W3 = (const float*)d_in[7];
  const float* g3 = (const float*)d_in[8];
  const float* b3 = (const float*)d_in[9];
  float* out = (float*)d_out;
  char* ws = (char*)d_ws;

  // workspace layout (~46.2 MB total)
  float* p1    = (float*)(ws);                 // 98,304 B
  float* gfp   = (float*)(ws + 131072);        // 3,932,160 B
  float* u2t   = (float*)(ws + 4194304);       // 41,943,040 B
  float* stats = (float*)(ws + 46137344);      // 384 f (sum/sq x3 layers)
  int*   prog  = (int*)(ws + 46138880);        // 4 ints: fps progress per batch

  hipMemsetAsync((void*)stats, 0, 1552, stream);   // stats (1536 B) + prog (16 B)
  hipLaunchKernelGGL(fpsknn_kernel, dim3(B_ + PERS), dim3(512), 0, stream,
                     p, p1, gfp, W1, stats, prog);
  hipLaunchKernelGGL(convB_kernel,  dim3(640),  dim3(256), 0, stream, gfp, W1, stats, g1, b1, W2, u2t);
  hipLaunchKernelGGL(stats2_kernel, dim3(512),  dim3(256), 0, stream, u2t, stats+128);
  hipLaunchKernelGGL(stats3_kernel, dim3(512),  dim3(256), 0, stream, u2t, W3, stats+128, g2, b2, stats+256);
  hipLaunchKernelGGL(out_kernel,    dim3(2048), dim3(256), 0, stream, u2t, W3, stats+128, g2, b2, stats+256, g3, b3, out);
}